// Round 4
// baseline (731.121 us; speedup 1.0000x reference)
//
#include <hip/hip_runtime.h>
#include <hip/hip_bf16.h>
#include <stdint.h>

#define NNODES 100000
#define DF 64
#define NEDGES 1600000
#define ND (NNODES * DF)     // 6,400,000
#define NB1 391              // ceil(NNODES/256)

// ---------- helpers ----------
static __device__ __forceinline__ float bf2f(unsigned short u) {
    union { uint32_t i; float f; } c; c.i = ((uint32_t)u) << 16; return c.f;
}
static __device__ __forceinline__ void unpack2(uint32_t u, float& lo, float& hi) {
    union { uint32_t i; float f; } a, b;
    a.i = u << 16; b.i = u & 0xFFFF0000u;
    lo = a.f; hi = b.f;
}
static __device__ __forceinline__ void load_row(const void* xv, int bf, size_t node, float* xr) {
    if (bf) {
        const uint4* xp = (const uint4*)((const unsigned short*)xv + node * DF);
        #pragma unroll
        for (int t = 0; t < 8; ++t) {
            uint4 q = xp[t];
            unpack2(q.x, xr[8*t+0], xr[8*t+1]);
            unpack2(q.y, xr[8*t+2], xr[8*t+3]);
            unpack2(q.z, xr[8*t+4], xr[8*t+5]);
            unpack2(q.w, xr[8*t+6], xr[8*t+7]);
        }
    } else {
        const float4* xp = (const float4*)((const float*)xv + node * DF);
        #pragma unroll
        for (int t = 0; t < 16; ++t) {
            float4 q = xp[t];
            xr[4*t+0] = q.x; xr[4*t+1] = q.y; xr[4*t+2] = q.z; xr[4*t+3] = q.w;
        }
    }
}

// ---------- dtype detector: flags[0]=bf16?, flags[1]=int64? ----------
__global__ void detect_k(const unsigned short* __restrict__ x,
                         const unsigned int* __restrict__ ei,
                         int* __restrict__ flags) {
    __shared__ int cnt_sane, cnt_odd_nz;
    if (threadIdx.x == 0) { cnt_sane = 0; cnt_odd_nz = 0; }
    __syncthreads();
    unsigned short s = x[threadIdx.x * 2];
    unsigned short m = s & 0x7FFF;
    if (m < 0x0080 || (m >= 0x3000 && m <= 0x4200)) atomicAdd(&cnt_sane, 1);
    if (threadIdx.x < 64) {
        if (ei[threadIdx.x * 2 + 1] != 0u) atomicAdd(&cnt_odd_nz, 1);
    }
    __syncthreads();
    if (threadIdx.x == 0) {
        flags[0] = (cnt_sane >= 192) ? 1 : 0;
        flags[1] = (cnt_odd_nz == 0) ? 1 : 0;
    }
}

// ---------- weight canonicalization ----------
// WfM/WfU: [128][64] fp32 (row j<64 = W[:, :64] row j ; j>=64 = W[:, 64:] row j-64)
// WfUT: [64][128] fp32, WfUT[k*128+j] = WfU[j*64+k]  (for LDS conflict-free k-loop)
// prm: b_msg[0:64) | b_upd[64:128) | gamma[128:192) | beta[192:256)
__global__ void wconv_k(const int* __restrict__ flags,
                        const void* __restrict__ Wm, const void* __restrict__ Wu,
                        const void* __restrict__ bm, const void* __restrict__ bu,
                        const void* __restrict__ ga, const void* __restrict__ be,
                        float* __restrict__ WfM, float* __restrict__ WfU,
                        float* __restrict__ WfUT, float* __restrict__ prm) {
    const int bf = flags[0];
    int i = blockIdx.x * 256 + threadIdx.x;
    if (i < 16384) {
        const void* src = (i < 8192) ? Wm : Wu;
        int ii = i & 8191, j = ii >> 6, k = ii & 63;
        int si = (j & 63) * 128 + ((j >> 6) ? 64 : 0) + k;
        float v = bf ? bf2f(((const unsigned short*)src)[si]) : ((const float*)src)[si];
        if (i < 8192) WfM[ii] = v;
        else { WfU[ii] = v; WfUT[k * 128 + j] = v; }
    } else if (i < 16384 + 256) {
        int t = i - 16384, which = t >> 6, k = t & 63;
        const void* p = (which == 0) ? bm : (which == 1) ? bu : (which == 2) ? ga : be;
        prm[t] = bf ? bf2f(((const unsigned short*)p)[k]) : ((const float*)p)[k];
    }
}

// ---------- projection: Ps = x@Wm_s^T ; Pt = x@Wm_t^T + b_msg (bf16 storage) ----------
__global__ __launch_bounds__(256) void proj_k(const int* __restrict__ flags,
                                              const void* __restrict__ xv,
                                              const float* __restrict__ WfM,
                                              const float* __restrict__ prm,
                                              __hip_bfloat16* __restrict__ Ps,
                                              __hip_bfloat16* __restrict__ Pt) {
    const int bf = flags[0];
    const int lane = threadIdx.x & 63;
    const int wib  = threadIdx.x >> 6;
    const int node = (blockIdx.x * 4 + wib) * 64 + lane;

    float xr[64];
    if (node < NNODES) {
        load_row(xv, bf, (size_t)node, xr);
    } else {
        #pragma unroll
        for (int t = 0; t < 64; ++t) xr[t] = 0.f;
    }

    for (int j = 0; j < 128; ++j) {
        const float* wr = WfM + j * 64;   // wave-uniform
        float a0 = 0.f, a1 = 0.f, a2 = 0.f, a3 = 0.f;
        #pragma unroll
        for (int k = 0; k < 64; k += 4) {
            a0 = fmaf(xr[k+0], wr[k+0], a0);
            a1 = fmaf(xr[k+1], wr[k+1], a1);
            a2 = fmaf(xr[k+2], wr[k+2], a2);
            a3 = fmaf(xr[k+3], wr[k+3], a3);
        }
        float acc = (a0 + a1) + (a2 + a3);
        if (node < NNODES) {
            if (j < 64) Ps[(size_t)node * DF + j] = __float2bfloat16(acc);
            else        Pt[(size_t)node * DF + (j - 64)] = __float2bfloat16(acc + prm[j - 64]);
        }
    }
}

// ---------- CSR build ----------
__global__ __launch_bounds__(256) void hist_k(const int* __restrict__ flags,
                                              const int* __restrict__ ei,
                                              int* __restrict__ Cnt) {
    const int i64 = flags[1];
    int i = blockIdx.x * 256 + threadIdx.x;
    int stride = gridDim.x * 256;
    for (int e = i; e < NEDGES; e += stride) {
        int tgt = i64 ? ei[4*e + 2] : ei[2*e + 1];
        if ((unsigned)tgt < NNODES) atomicAdd(Cnt + tgt, 1);
    }
}

// block-local exclusive scan of Cnt -> Row (local part) + per-block totals
__global__ __launch_bounds__(256) void scan1_k(const int* __restrict__ Cnt,
                                               int* __restrict__ Row,
                                               int* __restrict__ Bsum) {
    __shared__ int lds[256];
    int t = threadIdx.x, idx = blockIdx.x * 256 + t;
    int c = (idx < NNODES) ? Cnt[idx] : 0;
    lds[t] = c;
    __syncthreads();
    for (int off = 1; off < 256; off <<= 1) {
        int add = (t >= off) ? lds[t - off] : 0;
        __syncthreads();
        lds[t] += add;
        __syncthreads();
    }
    if (idx < NNODES) Row[idx] = lds[t] - c;          // exclusive
    if (t == 255) Bsum[blockIdx.x] = lds[255];        // block total
}

// exclusive scan of the 391 block totals
__global__ __launch_bounds__(512) void scan2_k(const int* __restrict__ Bsum,
                                               int* __restrict__ Boff) {
    __shared__ int lds[512];
    int t = threadIdx.x;
    int c = (t < NB1) ? Bsum[t] : 0;
    lds[t] = c;
    __syncthreads();
    for (int off = 1; off < 512; off <<= 1) {
        int add = (t >= off) ? lds[t - off] : 0;
        __syncthreads();
        lds[t] += add;
        __syncthreads();
    }
    if (t < NB1) Boff[t] = lds[t] - c;                // exclusive
}

// add block offsets; init write cursors; set Row[N]
__global__ __launch_bounds__(256) void scan3_k(int* __restrict__ Row,
                                               const int* __restrict__ Boff,
                                               int* __restrict__ Wpos) {
    int idx = blockIdx.x * 256 + threadIdx.x;
    if (idx < NNODES) {
        int v = Row[idx] + Boff[blockIdx.x];
        Row[idx] = v;
        Wpos[idx] = v;
    }
    if (blockIdx.x == 0 && threadIdx.x == 0) Row[NNODES] = NEDGES;
}

__global__ __launch_bounds__(256) void fill_k(const int* __restrict__ flags,
                                              const int* __restrict__ ei,
                                              int* __restrict__ Wpos,
                                              int* __restrict__ CsrSrc) {
    const int i64 = flags[1];
    int i = blockIdx.x * 256 + threadIdx.x;
    int stride = gridDim.x * 256;
    for (int e = i; e < NEDGES; e += stride) {
        int src, tgt;
        if (i64) { src = ei[4*e]; tgt = ei[4*e + 2]; }
        else     { src = ei[2*e]; tgt = ei[2*e + 1]; }
        if ((unsigned)tgt >= NNODES) continue;
        int slot = atomicAdd(Wpos + tgt, 1);
        CsrSrc[slot] = src;
    }
}

// ---------- fused aggregate + update + residual + LayerNorm ----------
// wave per target node (grid-stride). lane = feature.
__global__ __launch_bounds__(256) void aggupd_k(const int* __restrict__ flags,
                                                const void* __restrict__ xv,
                                                const __hip_bfloat16* __restrict__ Ps,
                                                const __hip_bfloat16* __restrict__ Pt,
                                                const int* __restrict__ Row,
                                                const int* __restrict__ CsrSrc,
                                                const float* __restrict__ WfUT,
                                                const float* __restrict__ prm,
                                                void* __restrict__ outv) {
    __shared__ float wu[8192];   // [k][j] : wu[k*128+j], j<64 = Wu_x, j>=64 = Wu_m
    const int bf = flags[0];
    const int tid = threadIdx.x;
    for (int i = tid; i < 8192; i += 256) wu[i] = WfUT[i];
    __syncthreads();

    const int lane = tid & 63;
    const int wib  = tid >> 6;
    const int wave0 = blockIdx.x * 4 + wib;
    const int nwave = gridDim.x * 4;
    const float bu_l = prm[64 + lane];
    const float ga_l = prm[128 + lane];
    const float be_l = prm[192 + lane];

    for (int t = wave0; t < NNODES; t += nwave) {
        const int e0 = Row[t], e1 = Row[t + 1];
        const float pt = __bfloat162float(Pt[(size_t)t * DF + lane]);

        float macc = 0.f;
        int e = e0;
        for (; e + 1 < e1; e += 2) {
            int s0 = CsrSrc[e], s1 = CsrSrc[e + 1];
            if ((unsigned)s0 >= NNODES) s0 = 0;
            if ((unsigned)s1 >= NNODES) s1 = 0;
            float v0 = __bfloat162float(Ps[(size_t)s0 * DF + lane]) + pt;
            float v1 = __bfloat162float(Ps[(size_t)s1 * DF + lane]) + pt;
            macc += fmaxf(v0, 0.f) + fmaxf(v1, 0.f);
        }
        if (e < e1) {
            int s0 = CsrSrc[e];
            if ((unsigned)s0 >= NNODES) s0 = 0;
            float v0 = __bfloat162float(Ps[(size_t)s0 * DF + lane]) + pt;
            macc += fmaxf(v0, 0.f);
        }
        const int deg = e1 - e0;
        const float ml = macc * (1.0f / (float)(deg > 0 ? deg : 1));

        // x row: lane holds x[t][lane]
        float xl;
        if (bf) xl = bf2f(((const unsigned short*)xv)[(size_t)t * DF + lane]);
        else    xl = ((const float*)xv)[(size_t)t * DF + lane];

        // update GEMV: u_l = bu_l + sum_k x_k*WuX[l,k] + m_k*WuM[l,k]
        float u = bu_l;
        #pragma unroll
        for (int k = 0; k < 64; ++k) {
            float xk = __shfl(xl, k, 64);
            float mk = __shfl(ml, k, 64);
            u = fmaf(xk, wu[k * 128 + lane], u);
            u = fmaf(mk, wu[k * 128 + 64 + lane], u);
        }
        float r = fmaxf(u, 0.f) + xl;

        // LayerNorm across 64 lanes (butterfly)
        float s = r, s2 = r * r;
        #pragma unroll
        for (int m = 1; m < 64; m <<= 1) {
            s  += __shfl_xor(s, m, 64);
            s2 += __shfl_xor(s2, m, 64);
        }
        float mu  = s * (1.0f / 64.0f);
        float var = fmaxf(s2 * (1.0f / 64.0f) - mu * mu, 0.f);
        float o = (r - mu) * rsqrtf(var + 1e-5f) * ga_l + be_l;

        size_t gi = (size_t)t * DF + lane;
        if (bf) ((__hip_bfloat16*)outv)[gi] = __float2bfloat16(o);
        else    ((float*)outv)[gi] = o;
    }
}

extern "C" void kernel_launch(void* const* d_in, const int* in_sizes, int n_in,
                              void* d_out, int out_size, void* d_ws, size_t ws_size,
                              hipStream_t stream) {
    const void* x  = d_in[0];
    const int*  ei = (const int*)d_in[1];
    const void* Wm = d_in[2];
    const void* bm = d_in[3];
    const void* Wu = d_in[4];
    const void* bu = d_in[5];
    const void* ga = d_in[6];
    const void* be = d_in[7];

    char* ws = (char*)d_ws;
    size_t off = 0;
    __hip_bfloat16* Ps = (__hip_bfloat16*)(ws + off); off += (size_t)ND * 2;       // 12.8 MB
    __hip_bfloat16* Pt = (__hip_bfloat16*)(ws + off); off += (size_t)ND * 2;       // 12.8 MB
    int*   CsrSrc = (int*)(ws + off); off += (size_t)NEDGES * 4;                   // 6.4 MB
    int*   Row    = (int*)(ws + off); off += (size_t)(NNODES + 1) * 4;
    int*   Wpos   = (int*)(ws + off); off += (size_t)NNODES * 4;
    int*   Cnt    = (int*)(ws + off); off += (size_t)NNODES * 4;                   // memset 0
    int*   flg    = (int*)(ws + off); off += 16;
    int*   Bsum   = (int*)(ws + off); off += 512 * 4;
    int*   Boff   = (int*)(ws + off); off += 512 * 4;
    float* WfM    = (float*)(ws + off); off += 8192 * 4;
    float* WfU    = (float*)(ws + off); off += 8192 * 4;
    float* WfUT   = (float*)(ws + off); off += 8192 * 4;
    float* prm    = (float*)(ws + off); off += 256 * 4;

    (void)hipMemsetAsync(Cnt, 0, (size_t)NNODES * 4, stream);

    detect_k<<<1, 256, 0, stream>>>((const unsigned short*)x, (const unsigned int*)ei, flg);
    wconv_k<<<65, 256, 0, stream>>>(flg, Wm, Wu, bm, bu, ga, be, WfM, WfU, WfUT, prm);

    proj_k<<<391, 256, 0, stream>>>(flg, x, WfM, prm, Ps, Pt);

    hist_k<<<2048, 256, 0, stream>>>(flg, ei, Cnt);
    scan1_k<<<NB1, 256, 0, stream>>>(Cnt, Row, Bsum);
    scan2_k<<<1, 512, 0, stream>>>(Bsum, Boff);
    scan3_k<<<NB1, 256, 0, stream>>>(Row, Boff, Wpos);
    fill_k<<<2048, 256, 0, stream>>>(flg, ei, Wpos, CsrSrc);

    aggupd_k<<<1024, 256, 0, stream>>>(flg, x, Ps, Pt, Row, CsrSrc, WfUT, prm, d_out);
}

// Round 5
// 562.610 us; speedup vs baseline: 1.2995x; 1.2995x over previous
//
#include <hip/hip_runtime.h>
#include <hip/hip_bf16.h>
#include <stdint.h>

#define NNODES 100000
#define DF 64
#define NEDGES 1600000
#define ND (NNODES * DF)     // 6,400,000
#define NB1 391              // ceil(NNODES/256)
#define CHUNK 512

// ---------- helpers ----------
static __device__ __forceinline__ float bf2f(unsigned short u) {
    union { uint32_t i; float f; } c; c.i = ((uint32_t)u) << 16; return c.f;
}
static __device__ __forceinline__ void unpack2(uint32_t u, float& lo, float& hi) {
    union { uint32_t i; float f; } a, b;
    a.i = u << 16; b.i = u & 0xFFFF0000u;
    lo = a.f; hi = b.f;
}

// ---------- dtype detector: flags[0]=bf16?, flags[1]=int64? ----------
__global__ void detect_k(const unsigned short* __restrict__ x,
                         const unsigned int* __restrict__ ei,
                         int* __restrict__ flags) {
    __shared__ int cnt_sane, cnt_odd_nz;
    if (threadIdx.x == 0) { cnt_sane = 0; cnt_odd_nz = 0; }
    __syncthreads();
    unsigned short s = x[threadIdx.x * 2];
    unsigned short m = s & 0x7FFF;
    if (m < 0x0080 || (m >= 0x3000 && m <= 0x4200)) atomicAdd(&cnt_sane, 1);
    if (threadIdx.x < 64) {
        if (ei[threadIdx.x * 2 + 1] != 0u) atomicAdd(&cnt_odd_nz, 1);
    }
    __syncthreads();
    if (threadIdx.x == 0) {
        flags[0] = (cnt_sane >= 192) ? 1 : 0;
        flags[1] = (cnt_odd_nz == 0) ? 1 : 0;
    }
}

// ---------- weight canonicalization -> fp32 ----------
// WfM/WfU: [128][64]; row j<64 = W[:, :64] row j ; row j>=64 = W[:, 64:] row j-64
// prm: b_msg[0:64) | b_upd[64:128) | gamma[128:192) | beta[192:256)
__global__ void wconv_k(const int* __restrict__ flags,
                        const void* __restrict__ Wm, const void* __restrict__ Wu,
                        const void* __restrict__ bm, const void* __restrict__ bu,
                        const void* __restrict__ ga, const void* __restrict__ be,
                        float* __restrict__ WfM, float* __restrict__ WfU,
                        float* __restrict__ prm) {
    const int bf = flags[0];
    int i = blockIdx.x * 256 + threadIdx.x;
    if (i < 16384) {
        const void* src = (i < 8192) ? Wm : Wu;
        float* dst = (i < 8192) ? WfM : WfU;
        int ii = i & 8191, j = ii >> 6, k = ii & 63;
        int si = (j & 63) * 128 + ((j >> 6) ? 64 : 0) + k;
        dst[ii] = bf ? bf2f(((const unsigned short*)src)[si]) : ((const float*)src)[si];
    } else if (i < 16384 + 256) {
        int t = i - 16384, which = t >> 6, k = t & 63;
        const void* p = (which == 0) ? bm : (which == 1) ? bu : (which == 2) ? ga : be;
        prm[t] = bf ? bf2f(((const unsigned short*)p)[k]) : ((const float*)p)[k];
    }
}

// ---------- projection: Ps = x @ Wm_s^T  (lane=feature, node wave-uniform) ----------
__global__ __launch_bounds__(256) void proj_k(const int* __restrict__ flags,
                                              const void* __restrict__ xv,
                                              const float* __restrict__ WfM,
                                              __hip_bfloat16* __restrict__ Ps) {
    const int bf = flags[0];
    const int lane = threadIdx.x & 63;
    const int wib = __builtin_amdgcn_readfirstlane(threadIdx.x >> 6);

    float w[64];
    {
        const float* r = WfM + lane * 64;     // Wm_s row `lane`
        #pragma unroll
        for (int k = 0; k < 64; ++k) w[k] = r[k];
    }

    const int w0 = blockIdx.x * 4 + wib;
    const int nw = gridDim.x * 4;
    for (int n = w0; n < NNODES; n += nw) {
        float a0 = 0.f, a1 = 0.f;
        if (bf) {
            const uint32_t* xw = (const uint32_t*)((const unsigned short*)xv + (size_t)n * DF);
            #pragma unroll
            for (int d = 0; d < 32; ++d) {
                float x0, x1; unpack2(xw[d], x0, x1);
                a0 = fmaf(x0, w[2*d],   a0);
                a1 = fmaf(x1, w[2*d+1], a1);
            }
        } else {
            const float* xf = (const float*)xv + (size_t)n * DF;
            #pragma unroll
            for (int d = 0; d < 64; d += 2) {
                a0 = fmaf(xf[d],   w[d],   a0);
                a1 = fmaf(xf[d+1], w[d+1], a1);
            }
        }
        Ps[(size_t)n * DF + lane] = __float2bfloat16(a0 + a1);  // coalesced 128B/wave
    }
}

// ---------- CSR build ----------
__global__ __launch_bounds__(256) void hist_k(const int* __restrict__ flags,
                                              const int* __restrict__ ei,
                                              int* __restrict__ Cnt) {
    const int i64 = flags[1];
    int i = blockIdx.x * 256 + threadIdx.x;
    int stride = gridDim.x * 256;
    for (int e = i; e < NEDGES; e += stride) {
        int tgt = i64 ? ei[4*e + 2] : ei[2*e + 1];
        if ((unsigned)tgt < NNODES) atomicAdd(Cnt + tgt, 1);
    }
}

__global__ __launch_bounds__(256) void scan1_k(const int* __restrict__ Cnt,
                                               int* __restrict__ Row,
                                               int* __restrict__ Bsum) {
    __shared__ int lds[256];
    int t = threadIdx.x, idx = blockIdx.x * 256 + t;
    int c = (idx < NNODES) ? Cnt[idx] : 0;
    lds[t] = c;
    __syncthreads();
    for (int off = 1; off < 256; off <<= 1) {
        int add = (t >= off) ? lds[t - off] : 0;
        __syncthreads();
        lds[t] += add;
        __syncthreads();
    }
    if (idx < NNODES) Row[idx] = lds[t] - c;
    if (t == 255) Bsum[blockIdx.x] = lds[255];
}

__global__ __launch_bounds__(512) void scan2_k(const int* __restrict__ Bsum,
                                               int* __restrict__ Boff) {
    __shared__ int lds[512];
    int t = threadIdx.x;
    int c = (t < NB1) ? Bsum[t] : 0;
    lds[t] = c;
    __syncthreads();
    for (int off = 1; off < 512; off <<= 1) {
        int add = (t >= off) ? lds[t - off] : 0;
        __syncthreads();
        lds[t] += add;
        __syncthreads();
    }
    if (t < NB1) Boff[t] = lds[t] - c;
}

__global__ __launch_bounds__(256) void scan3_k(int* __restrict__ Row,
                                               const int* __restrict__ Boff,
                                               int* __restrict__ Wpos) {
    int idx = blockIdx.x * 256 + threadIdx.x;
    if (idx < NNODES) {
        int v = Row[idx] + Boff[blockIdx.x];
        Row[idx] = v;
        Wpos[idx] = v;
    }
    if (blockIdx.x == 0 && threadIdx.x == 0) Row[NNODES] = NEDGES;
}

__global__ __launch_bounds__(256) void fill_k(const int* __restrict__ flags,
                                              const int* __restrict__ ei,
                                              int* __restrict__ Wpos,
                                              int* __restrict__ CsrSrc) {
    const int i64 = flags[1];
    int i = blockIdx.x * 256 + threadIdx.x;
    int stride = gridDim.x * 256;
    for (int e = i; e < NEDGES; e += stride) {
        int src, tgt;
        if (i64) { src = ei[4*e]; tgt = ei[4*e + 2]; }
        else     { src = ei[2*e]; tgt = ei[2*e + 1]; }
        if ((unsigned)tgt >= NNODES) continue;
        int slot = atomicAdd(Wpos + tgt, 1);
        CsrSrc[slot] = src;
    }
}

// ---------- chunked segmented aggregation over CSR ----------
// wave owns edges [eA, eB); Pt computed on the fly per segment; complete
// segments flushed with plain stores, boundary partials with atomicAdd.
__global__ __launch_bounds__(256) void agg_k(const int* __restrict__ flags,
                                             const void* __restrict__ xv,
                                             const __hip_bfloat16* __restrict__ Ps,
                                             const float* __restrict__ WfM,
                                             const float* __restrict__ prm,
                                             const int* __restrict__ Row,
                                             const int* __restrict__ CsrSrc,
                                             float* __restrict__ Msg) {
    const int bf = flags[0];
    const int lane = threadIdx.x & 63;
    const int wib = __builtin_amdgcn_readfirstlane(threadIdx.x >> 6);
    const int wid = blockIdx.x * 4 + wib;
    const int eA = wid * CHUNK;
    if (eA >= NEDGES) return;
    const int eB = (eA + CHUNK < NEDGES) ? eA + CHUNK : NEDGES;

    float wt[64];   // Wm_t row `lane`
    {
        const float* r = WfM + (64 + lane) * 64;
        #pragma unroll
        for (int k = 0; k < 64; ++k) wt[k] = r[k];
    }
    const float bm = prm[lane];

    // binary search: largest t with Row[t] <= eA
    int lo = 0, hi = NNODES;
    while (hi - lo > 1) {
        int mid = (lo + hi) >> 1;
        if (Row[mid] <= eA) lo = mid; else hi = mid;
    }
    int t = lo;
    int e = eA;
    while (e < eB) {
        const int segS = Row[t], segE = Row[t + 1];
        if (segE <= e) { ++t; continue; }          // skip empty targets

        // pt = b_msg + x[t] @ Wm_t^T   (x row wave-uniform -> scalar loads)
        float pt = bm;
        if (bf) {
            const uint32_t* xw = (const uint32_t*)((const unsigned short*)xv + (size_t)t * DF);
            #pragma unroll
            for (int d = 0; d < 32; ++d) {
                float x0, x1; unpack2(xw[d], x0, x1);
                pt = fmaf(x0, wt[2*d],   pt);
                pt = fmaf(x1, wt[2*d+1], pt);
            }
        } else {
            const float* xf = (const float*)xv + (size_t)t * DF;
            #pragma unroll
            for (int d = 0; d < 64; ++d) pt = fmaf(xf[d], wt[d], pt);
        }

        const int lim = (segE < eB) ? segE : eB;
        float macc = 0.f;
        int i = e;
        for (; i + 4 <= lim; i += 4) {             // 4 independent gathers in flight
            int s0 = CsrSrc[i], s1 = CsrSrc[i+1], s2 = CsrSrc[i+2], s3 = CsrSrc[i+3];
            if ((unsigned)s0 >= NNODES) s0 = 0;
            if ((unsigned)s1 >= NNODES) s1 = 0;
            if ((unsigned)s2 >= NNODES) s2 = 0;
            if ((unsigned)s3 >= NNODES) s3 = 0;
            float v0 = __bfloat162float(Ps[(size_t)s0 * DF + lane]);
            float v1 = __bfloat162float(Ps[(size_t)s1 * DF + lane]);
            float v2 = __bfloat162float(Ps[(size_t)s2 * DF + lane]);
            float v3 = __bfloat162float(Ps[(size_t)s3 * DF + lane]);
            macc += fmaxf(v0 + pt, 0.f) + fmaxf(v1 + pt, 0.f)
                  + fmaxf(v2 + pt, 0.f) + fmaxf(v3 + pt, 0.f);
        }
        for (; i < lim; ++i) {
            int s0 = CsrSrc[i];
            if ((unsigned)s0 >= NNODES) s0 = 0;
            macc += fmaxf(__bfloat162float(Ps[(size_t)s0 * DF + lane]) + pt, 0.f);
        }

        float* dst = Msg + (size_t)t * DF + lane;
        if (segS >= eA && segE <= eB) *dst = macc; // exclusive owner: plain store
        else atomicAdd(dst, macc);                 // chunk-boundary partial
        e = lim;
        if (e >= segE) ++t;
    }
}

// ---------- update + residual + LayerNorm (lane=feature, node wave-uniform) ----------
__global__ __launch_bounds__(256) void upd_k(const int* __restrict__ flags,
                                             const void* __restrict__ xv,
                                             const float* __restrict__ Msg,
                                             const int* __restrict__ Row,
                                             const float* __restrict__ WfU,
                                             const float* __restrict__ prm,
                                             void* __restrict__ outv) {
    const int bf = flags[0];
    const int lane = threadIdx.x & 63;
    const int wib = __builtin_amdgcn_readfirstlane(threadIdx.x >> 6);

    float wx[64], wm[64];
    {
        const float* r0 = WfU + lane * 64;          // Wu_x row `lane`
        const float* r1 = WfU + (lane + 64) * 64;   // Wu_m row `lane`
        #pragma unroll
        for (int k = 0; k < 64; ++k) { wx[k] = r0[k]; wm[k] = r1[k]; }
    }
    const float bu = prm[64 + lane];
    const float ga = prm[128 + lane];
    const float be = prm[192 + lane];

    const int w0 = blockIdx.x * 4 + wib;
    const int nw = gridDim.x * 4;
    for (int n = w0; n < NNODES; n += nw) {
        float da0 = 0.f, da1 = 0.f, db0 = 0.f, db1 = 0.f;
        float xl;
        const float* mrow = Msg + (size_t)n * DF;   // wave-uniform
        if (bf) {
            const uint32_t* xw = (const uint32_t*)((const unsigned short*)xv + (size_t)n * DF);
            #pragma unroll
            for (int d = 0; d < 32; ++d) {
                float x0, x1; unpack2(xw[d], x0, x1);
                da0 = fmaf(x0, wx[2*d],   da0);
                da1 = fmaf(x1, wx[2*d+1], da1);
            }
            xl = bf2f(((const unsigned short*)xv)[(size_t)n * DF + lane]);
        } else {
            const float* xf = (const float*)xv + (size_t)n * DF;
            #pragma unroll
            for (int d = 0; d < 64; d += 2) {
                da0 = fmaf(xf[d],   wx[d],   da0);
                da1 = fmaf(xf[d+1], wx[d+1], da1);
            }
            xl = ((const float*)xv)[(size_t)n * DF + lane];
        }
        #pragma unroll
        for (int d = 0; d < 64; d += 2) {
            db0 = fmaf(mrow[d],   wm[d],   db0);
            db1 = fmaf(mrow[d+1], wm[d+1], db1);
        }
        int deg = Row[n + 1] - Row[n];
        float inv = 1.0f / (float)(deg > 0 ? deg : 1);
        float u = fmaxf(fmaf(db0 + db1, inv, (da0 + da1) + bu), 0.f);
        float r = u + xl;

        float s = r, s2 = r * r;
        #pragma unroll
        for (int m = 1; m < 64; m <<= 1) {
            s  += __shfl_xor(s, m, 64);
            s2 += __shfl_xor(s2, m, 64);
        }
        float mu  = s * (1.0f / 64.0f);
        float var = fmaxf(s2 * (1.0f / 64.0f) - mu * mu, 0.f);
        float o = (r - mu) * rsqrtf(var + 1e-5f) * ga + be;

        size_t gi = (size_t)n * DF + lane;
        if (bf) ((__hip_bfloat16*)outv)[gi] = __float2bfloat16(o);
        else    ((float*)outv)[gi] = o;
    }
}

extern "C" void kernel_launch(void* const* d_in, const int* in_sizes, int n_in,
                              void* d_out, int out_size, void* d_ws, size_t ws_size,
                              hipStream_t stream) {
    const void* x  = d_in[0];
    const int*  ei = (const int*)d_in[1];
    const void* Wm = d_in[2];
    const void* bm = d_in[3];
    const void* Wu = d_in[4];
    const void* bu = d_in[5];
    const void* ga = d_in[6];
    const void* be = d_in[7];

    char* ws = (char*)d_ws;
    size_t off = 0;
    __hip_bfloat16* Ps = (__hip_bfloat16*)(ws + off); off += (size_t)ND * 2;   // 12.8 MB
    int*   CsrSrc = (int*)(ws + off); off += (size_t)NEDGES * 4;               // 6.4 MB
    float* Msg    = (float*)(ws + off); off += (size_t)ND * 4;                 // 25.6 MB (memset)
    int*   Cnt    = (int*)(ws + off); off += (size_t)NNODES * 4;               // (memset)
    int*   Row    = (int*)(ws + off); off += (size_t)(NNODES + 1) * 4;
    int*   Wpos   = (int*)(ws + off); off += (size_t)NNODES * 4;
    int*   flg    = (int*)(ws + off); off += 16;
    int*   Bsum   = (int*)(ws + off); off += 512 * 4;
    int*   Boff   = (int*)(ws + off); off += 512 * 4;
    float* WfM    = (float*)(ws + off); off += 8192 * 4;
    float* WfU    = (float*)(ws + off); off += 8192 * 4;
    float* prm    = (float*)(ws + off); off += 256 * 4;

    (void)hipMemsetAsync(Msg, 0, (size_t)ND * 4 + (size_t)NNODES * 4, stream);

    detect_k<<<1, 256, 0, stream>>>((const unsigned short*)x, (const unsigned int*)ei, flg);
    wconv_k<<<65, 256, 0, stream>>>(flg, Wm, Wu, bm, bu, ga, be, WfM, WfU, prm);

    proj_k<<<391, 256, 0, stream>>>(flg, x, WfM, Ps);

    hist_k<<<2048, 256, 0, stream>>>(flg, ei, Cnt);
    scan1_k<<<NB1, 256, 0, stream>>>(Cnt, Row, Bsum);
    scan2_k<<<1, 512, 0, stream>>>(Bsum, Boff);
    scan3_k<<<NB1, 256, 0, stream>>>(Row, Boff, Wpos);
    fill_k<<<2048, 256, 0, stream>>>(flg, ei, Wpos, CsrSrc);

    agg_k<<<(NEDGES / CHUNK + 3) / 4, 256, 0, stream>>>(flg, x, Ps, WfM, prm, Row, CsrSrc, Msg);

    upd_k<<<391, 256, 0, stream>>>(flg, x, Msg, Row, WfU, prm, d_out);
}